// Round 1
// baseline (854.915 us; speedup 1.0000x reference)
//
#include <hip/hip_runtime.h>

#define HD 128  // hidden/feature dim (fixed by problem)

// ---------------- degree / CSR build ----------------
__global__ void k_deg_count(const int* __restrict__ row, int E, int* __restrict__ deg) {
  int e = blockIdx.x * blockDim.x + threadIdx.x;
  if (e < E) atomicAdd(&deg[row[e]], 1);
}

__global__ void k_scan_block(const int* __restrict__ deg, int* __restrict__ offs,
                             int* __restrict__ partials, int N) {
  __shared__ int s[256];
  int t = threadIdx.x;
  int i = blockIdx.x * 256 + t;
  int v = (i < N) ? deg[i] : 0;
  s[t] = v;
  __syncthreads();
  #pragma unroll
  for (int off = 1; off < 256; off <<= 1) {
    int x = (t >= off) ? s[t - off] : 0;
    __syncthreads();
    s[t] += x;
    __syncthreads();
  }
  if (i < N) offs[i] = s[t] - v;          // exclusive scan within block
  if (t == 255) partials[blockIdx.x] = s[255];
}

__global__ void k_scan_partials(int* __restrict__ partials, int P) {
  __shared__ int s[256];
  int t = threadIdx.x;
  int v = (t < P) ? partials[t] : 0;
  s[t] = v;
  __syncthreads();
  #pragma unroll
  for (int off = 1; off < 256; off <<= 1) {
    int x = (t >= off) ? s[t - off] : 0;
    __syncthreads();
    s[t] += x;
    __syncthreads();
  }
  if (t < P) partials[t] = s[t] - v;      // exclusive
}

__global__ void k_scan_finalize(int* __restrict__ offs, const int* __restrict__ partials,
                                const int* __restrict__ deg, float* __restrict__ dis,
                                int N, int E) {
  int i = blockIdx.x * 256 + threadIdx.x;
  if (i < N) {
    offs[i] += partials[blockIdx.x];
    int d = deg[i];
    dis[i] = (d > 0) ? (1.0f / sqrtf((float)d)) : 0.0f;
  }
  if (blockIdx.x == 0 && threadIdx.x == 0) offs[N] = E;
}

__global__ void k_csr_fill(const int* __restrict__ row, const int* __restrict__ col,
                           int E, int* __restrict__ cursor, int* __restrict__ csr_col) {
  int e = blockIdx.x * blockDim.x + threadIdx.x;
  if (e < E) {
    int r = row[e];
    int p = atomicAdd(&cursor[r], 1);
    csr_col[p] = col[e];
  }
}

// ---------------- dense GEMM: C = op(A[N,128] @ W[128,128] + b) (*scale[row]) --------
// block = 256 threads, tile = 64 rows x 128 cols, each thread = 8 rows x 4 cols.
template<bool RELU, bool SCALE>
__global__ __launch_bounds__(256, 2) void k_gemm128(
    const float* __restrict__ A, const float* __restrict__ W,
    const float* __restrict__ bias, const float* __restrict__ scale,
    float* __restrict__ C, int N) {
  __shared__ float As[32][68];    // k-major (transposed) A chunk, padded to keep 16B align
  __shared__ float Ws[32][128];
  const int tid = threadIdx.x;
  const int tx = tid & 31;        // cols 4*tx .. 4*tx+3
  const int ty = tid >> 5;        // rows ty*8 .. ty*8+7
  const int row0 = blockIdx.x * 64;
  float4 acc[8];
  #pragma unroll
  for (int i = 0; i < 8; ++i) acc[i] = make_float4(0.f, 0.f, 0.f, 0.f);

  for (int kb = 0; kb < HD; kb += 32) {
    // stage A chunk (64 rows x 32 k), transposed into LDS
    #pragma unroll
    for (int l = 0; l < 2; ++l) {
      int lid = tid * 2 + l;      // 0..511
      int r = lid >> 3;
      int q = lid & 7;
      float4 a = make_float4(0.f, 0.f, 0.f, 0.f);
      int gr = row0 + r;
      if (gr < N) a = *(const float4*)(A + (size_t)gr * HD + kb + 4 * q);
      As[4 * q + 0][r] = a.x;
      As[4 * q + 1][r] = a.y;
      As[4 * q + 2][r] = a.z;
      As[4 * q + 3][r] = a.w;
    }
    // stage W chunk (32 k x 128 cols)
    #pragma unroll
    for (int l = 0; l < 4; ++l) {
      int lid = tid + 256 * l;    // 0..1023
      int kk = lid >> 5;
      int c4 = lid & 31;
      *(float4*)&Ws[kk][c4 * 4] = *(const float4*)(W + (size_t)(kb + kk) * HD + 4 * c4);
    }
    __syncthreads();
    #pragma unroll
    for (int kk = 0; kk < 32; ++kk) {
      float4 w  = *(float4*)&Ws[kk][tx * 4];
      float4 a0 = *(float4*)&As[kk][ty * 8];
      float4 a1 = *(float4*)&As[kk][ty * 8 + 4];
      float av[8] = {a0.x, a0.y, a0.z, a0.w, a1.x, a1.y, a1.z, a1.w};
      #pragma unroll
      for (int i = 0; i < 8; ++i) {
        acc[i].x = fmaf(av[i], w.x, acc[i].x);
        acc[i].y = fmaf(av[i], w.y, acc[i].y);
        acc[i].z = fmaf(av[i], w.z, acc[i].z);
        acc[i].w = fmaf(av[i], w.w, acc[i].w);
      }
    }
    __syncthreads();
  }
  float4 bv = *(const float4*)(bias + tx * 4);
  #pragma unroll
  for (int i = 0; i < 8; ++i) {
    int r = row0 + ty * 8 + i;
    if (r < N) {
      float4 o;
      o.x = acc[i].x + bv.x;
      o.y = acc[i].y + bv.y;
      o.z = acc[i].z + bv.z;
      o.w = acc[i].w + bv.w;
      if (RELU) {
        o.x = fmaxf(o.x, 0.f); o.y = fmaxf(o.y, 0.f);
        o.z = fmaxf(o.z, 0.f); o.w = fmaxf(o.w, 0.f);
      }
      if (SCALE) {
        float s = scale[r];
        o.x *= s; o.y *= s; o.z *= s; o.w *= s;
      }
      *(float4*)(C + (size_t)r * HD + tx * 4) = o;
    }
  }
}

// ---------------- CSR aggregate: out[r] = relu(dis[r] * sum_{e in r} T[col_e]) ------
// one wave (64 lanes) per node; lane handles 2 consecutive floats (512B/row coalesced)
__global__ __launch_bounds__(256) void k_aggregate(
    const float* __restrict__ T, const int* __restrict__ offs,
    const int* __restrict__ csr_col, const float* __restrict__ dis,
    float* __restrict__ out, int N) {
  int gw = (blockIdx.x * blockDim.x + threadIdx.x) >> 6;
  int lane = threadIdx.x & 63;
  if (gw >= N) return;
  int beg = offs[gw];
  int end = offs[gw + 1];
  const float* Tl = T + lane * 2;
  float ax = 0.f, ay = 0.f;
  int e = beg;
  for (; e + 4 <= end; e += 4) {
    int c0 = csr_col[e + 0], c1 = csr_col[e + 1];
    int c2 = csr_col[e + 2], c3 = csr_col[e + 3];
    float2 v0 = *(const float2*)(Tl + (size_t)c0 * HD);
    float2 v1 = *(const float2*)(Tl + (size_t)c1 * HD);
    float2 v2 = *(const float2*)(Tl + (size_t)c2 * HD);
    float2 v3 = *(const float2*)(Tl + (size_t)c3 * HD);
    ax += v0.x + v1.x + v2.x + v3.x;
    ay += v0.y + v1.y + v2.y + v3.y;
  }
  for (; e < end; ++e) {
    int c = csr_col[e];
    float2 v = *(const float2*)(Tl + (size_t)c * HD);
    ax += v.x;
    ay += v.y;
  }
  float dr = dis[gw];
  float2 o;
  o.x = fmaxf(ax * dr, 0.f);
  o.y = fmaxf(ay * dr, 0.f);
  *(float2*)(out + (size_t)gw * HD + lane * 2) = o;
}

// ---------------- mean-pool partial sums ----------------
__global__ void k_pool(const float* __restrict__ X, float* __restrict__ pool, int N) {
  int c = threadIdx.x & 127;
  int half = threadIdx.x >> 7;
  int r0 = blockIdx.x * 256 + half;
  float acc = 0.f;
  for (int i = 0; i < 128; ++i) {
    int r = r0 + 2 * i;
    if (r < N) acc += X[(size_t)r * HD + c];
  }
  atomicAdd(&pool[c], acc);
}

// ---------------- final similarity MLP (tiny) ----------------
__global__ void k_final(const float* __restrict__ pool1, const float* __restrict__ pool2,
                        const float* __restrict__ W1, const float* __restrict__ b1,
                        const float* __restrict__ W2, const float* __restrict__ b2,
                        float* __restrict__ out, float invN) {
  __shared__ float cs[512];
  __shared__ float red[2];
  int t = threadIdx.x;  // 128 threads
  float g1 = pool1[t] * invN;
  float g2 = pool2[t] * invN;
  cs[t] = g1;
  cs[128 + t] = g2;
  cs[256 + t] = fabsf(g1 - g2);
  cs[384 + t] = g1 * g2;
  __syncthreads();
  float acc = b1[t];
  for (int i = 0; i < 512; ++i) acc = fmaf(cs[i], W1[(size_t)i * 128 + t], acc);
  float h = fmaxf(acc, 0.f);
  float v = h * W2[t];
  #pragma unroll
  for (int off = 32; off > 0; off >>= 1) v += __shfl_down(v, off, 64);
  if ((t & 63) == 0) red[t >> 6] = v;
  __syncthreads();
  if (t == 0) out[0] = red[0] + red[1] + b2[0];
}

extern "C" void kernel_launch(void* const* d_in, const int* in_sizes, int n_in,
                              void* d_out, int out_size, void* d_ws, size_t ws_size,
                              hipStream_t stream) {
  const float* x[2]      = {(const float*)d_in[0], (const float*)d_in[2]};
  const int*   ei[2]     = {(const int*)d_in[1], (const int*)d_in[3]};
  const float* enc_w1    = (const float*)d_in[4];
  const float* enc_b1    = (const float*)d_in[5];
  const float* enc_w2    = (const float*)d_in[6];
  const float* enc_b2    = (const float*)d_in[7];
  const float* conv_w[2] = {(const float*)d_in[8], (const float*)d_in[10]};  // layer 1, 2
  const float* conv_b[2] = {(const float*)d_in[9], (const float*)d_in[11]};
  const float* sim_w1    = (const float*)d_in[12];
  const float* sim_b1    = (const float*)d_in[13];
  const float* sim_w2    = (const float*)d_in[14];
  const float* sim_b2    = (const float*)d_in[15];

  const int N = in_sizes[0] / HD;
  const int E = in_sizes[1] / 2;

  // workspace layout (fp32-aligned; ~81 MB for N=50000, E=800000)
  float* p = (float*)d_ws;
  float* bufA = p; p += (size_t)N * HD;
  float* bufB = p; p += (size_t)N * HD;
  float* bufT = p; p += (size_t)N * HD;
  float* dis  = p; p += N;
  float* pool = p; p += 256;          // pool1[128] | pool2[128] (sums)
  int* ip = (int*)p;
  int* deg      = ip; ip += N;
  int* offs     = ip; ip += N + 1;
  int* cursor   = ip; ip += N;
  int* partials = ip; ip += 256;
  int* csr_col  = ip; ip += E;

  const int scanBlocks = (N + 255) / 256;   // 196 for N=50000 (<=256 required)
  const int gemmBlocks = (N + 63) / 64;
  const int aggBlocks  = (N + 3) / 4;       // 4 waves/block, 1 node/wave
  const int edgeBlocks = (E + 255) / 256;

  hipMemsetAsync(pool, 0, 256 * sizeof(float), stream);

  for (int g = 0; g < 2; ++g) {
    const int* row = ei[g];
    const int* col = ei[g] + E;

    // CSR + degree (shared by both conv layers of this graph)
    hipMemsetAsync(deg, 0, (size_t)N * sizeof(int), stream);
    k_deg_count<<<edgeBlocks, 256, 0, stream>>>(row, E, deg);
    k_scan_block<<<scanBlocks, 256, 0, stream>>>(deg, offs, partials, N);
    k_scan_partials<<<1, 256, 0, stream>>>(partials, scanBlocks);
    k_scan_finalize<<<scanBlocks, 256, 0, stream>>>(offs, partials, deg, dis, N, E);
    hipMemcpyAsync(cursor, offs, (size_t)N * sizeof(int), hipMemcpyDeviceToDevice, stream);
    k_csr_fill<<<edgeBlocks, 256, 0, stream>>>(row, col, E, cursor, csr_col);

    // encoder MLP
    k_gemm128<true,  false><<<gemmBlocks, 256, 0, stream>>>(x[g], enc_w1, enc_b1, nullptr, bufA, N);
    k_gemm128<false, false><<<gemmBlocks, 256, 0, stream>>>(bufA, enc_w2, enc_b2, nullptr, bufB, N);
    // conv1: T = (h@W+b)*dis[row];  out = relu(dis[r]*sum T[col])
    k_gemm128<false, true ><<<gemmBlocks, 256, 0, stream>>>(bufB, conv_w[0], conv_b[0], dis, bufT, N);
    k_aggregate<<<aggBlocks, 256, 0, stream>>>(bufT, offs, csr_col, dis, bufA, N);
    // conv2
    k_gemm128<false, true ><<<gemmBlocks, 256, 0, stream>>>(bufA, conv_w[1], conv_b[1], dis, bufT, N);
    k_aggregate<<<aggBlocks, 256, 0, stream>>>(bufT, offs, csr_col, dis, bufB, N);
    // mean pool (sums; divided by N in final kernel)
    k_pool<<<(N + 255) / 256, 256, 0, stream>>>(bufB, pool + g * 128, N);
  }

  k_final<<<1, 128, 0, stream>>>(pool, pool + 128, sim_w1, sim_b1, sim_w2, sim_b2,
                                 (float*)d_out, 1.0f / (float)N);
}

// Round 2
// 754.667 us; speedup vs baseline: 1.1328x; 1.1328x over previous
//
#include <hip/hip_runtime.h>
#include <hip/hip_bf16.h>

#define HD 128  // hidden/feature dim (fixed by problem)

typedef short bf16x8 __attribute__((ext_vector_type(8)));
typedef float f32x4 __attribute__((ext_vector_type(4)));

static __device__ inline unsigned short f2b(float f) {
  __hip_bfloat16 h = __float2bfloat16(f);   // RNE
  return *(unsigned short*)&h;
}
static __device__ inline float b2f(unsigned short u) {
  unsigned int x = ((unsigned int)u) << 16;
  return __uint_as_float(x);
}
static __device__ inline float unpack_lo(unsigned int v) {
  return __uint_as_float(v << 16);
}
static __device__ inline float unpack_hi(unsigned int v) {
  return __uint_as_float(v & 0xffff0000u);
}

// ---------------- degree / CSR build ----------------
__global__ void k_deg_count(const int* __restrict__ row, int E, int* __restrict__ deg) {
  int e = blockIdx.x * blockDim.x + threadIdx.x;
  if (e < E) atomicAdd(&deg[row[e]], 1);
}

__global__ void k_scan_block(const int* __restrict__ deg, int* __restrict__ offs,
                             int* __restrict__ partials, int N) {
  __shared__ int s[256];
  int t = threadIdx.x;
  int i = blockIdx.x * 256 + t;
  int v = (i < N) ? deg[i] : 0;
  s[t] = v;
  __syncthreads();
  #pragma unroll
  for (int off = 1; off < 256; off <<= 1) {
    int x = (t >= off) ? s[t - off] : 0;
    __syncthreads();
    s[t] += x;
    __syncthreads();
  }
  if (i < N) offs[i] = s[t] - v;
  if (t == 255) partials[blockIdx.x] = s[255];
}

__global__ void k_scan_partials(int* __restrict__ partials, int P) {
  __shared__ int s[256];
  int t = threadIdx.x;
  int v = (t < P) ? partials[t] : 0;
  s[t] = v;
  __syncthreads();
  #pragma unroll
  for (int off = 1; off < 256; off <<= 1) {
    int x = (t >= off) ? s[t - off] : 0;
    __syncthreads();
    s[t] += x;
    __syncthreads();
  }
  if (t < P) partials[t] = s[t] - v;
}

__global__ void k_scan_finalize(int* __restrict__ offs, const int* __restrict__ partials,
                                const int* __restrict__ deg, float* __restrict__ dis,
                                int N, int E) {
  int i = blockIdx.x * 256 + threadIdx.x;
  if (i < N) {
    offs[i] += partials[blockIdx.x];
    int d = deg[i];
    dis[i] = (d > 0) ? (1.0f / sqrtf((float)d)) : 0.0f;
  }
  if (blockIdx.x == 0 && threadIdx.x == 0) offs[N] = E;
}

__global__ void k_csr_fill(const int* __restrict__ row, const int* __restrict__ col,
                           int E, int* __restrict__ cursor, int* __restrict__ csr_col) {
  int e = blockIdx.x * blockDim.x + threadIdx.x;
  if (e < E) {
    int r = row[e];
    int p = atomicAdd(&cursor[r], 1);
    csr_col[p] = col[e];
  }
}

// ---------------- conversions ----------------
// fp32 [N,128] -> bf16 (packed), 4 elems/thread
__global__ void k_cvt_x(const float* __restrict__ X, unsigned short* __restrict__ O, int total4) {
  int i = blockIdx.x * 256 + threadIdx.x;
  if (i < total4) {
    float4 v = *(const float4*)(X + (size_t)i * 4);
    unsigned int p0 = (unsigned int)f2b(v.x) | ((unsigned int)f2b(v.y) << 16);
    unsigned int p1 = (unsigned int)f2b(v.z) | ((unsigned int)f2b(v.w) << 16);
    ((unsigned int*)O)[i * 2 + 0] = p0;
    ((unsigned int*)O)[i * 2 + 1] = p1;
  }
}

// W [128,128] fp32 (k-major) -> transposed bf16 hi/lo: out[n*128+k]
__global__ void k_cvt_w(const float* __restrict__ W, unsigned short* __restrict__ hi,
                        unsigned short* __restrict__ lo) {
  int idx = blockIdx.x * 256 + threadIdx.x;  // 16384
  int n = idx & 127, k = idx >> 7;
  float w = W[(size_t)k * HD + n];
  unsigned short h = f2b(w);
  hi[(size_t)n * HD + k] = h;
  lo[(size_t)n * HD + k] = f2b(w - b2f(h));
}

// ---------------- MFMA GEMM: C = op(A[N,128] @ W[128,128] + b) (*scale[row]) --------
// A bf16, W pre-transposed+split bf16 hi/lo, C bf16. No LDS: wave = 32 rows x 128 cols.
// A-frag layout: A[m=lane&15][k=(lane>>4)*8+j]; B-frag: B[n=lane&15][k=(lane>>4)*8+j]
// (W^T row-major so 8 k's are contiguous). C/D: col=lane&15, row=(lane>>4)*4+reg.
template<bool RELU, bool SCALE>
__global__ __launch_bounds__(256, 2) void k_gemm_mfma(
    const unsigned short* __restrict__ A, const unsigned short* __restrict__ Whi,
    const unsigned short* __restrict__ Wlo, const float* __restrict__ bias,
    const float* __restrict__ scale, unsigned short* __restrict__ C, int N) {
  const int wave = threadIdx.x >> 6;
  const int lane = threadIdx.x & 63;
  const int n16 = lane & 15;
  const int q = lane >> 4;
  const int rowbase = blockIdx.x * 128 + wave * 32;

  f32x4 acc[2][8];
  #pragma unroll
  for (int m = 0; m < 2; ++m)
    #pragma unroll
    for (int n = 0; n < 8; ++n) acc[m][n] = (f32x4){0.f, 0.f, 0.f, 0.f};

  int r0 = rowbase + n16;       if (r0 >= N) r0 = N - 1;
  int r1 = rowbase + 16 + n16;  if (r1 >= N) r1 = N - 1;
  const unsigned short* a0p = A + (size_t)r0 * HD + q * 8;
  const unsigned short* a1p = A + (size_t)r1 * HD + q * 8;
  const unsigned short* bhp = Whi + (size_t)n16 * HD + q * 8;
  const unsigned short* blp = Wlo + (size_t)n16 * HD + q * 8;

  #pragma unroll
  for (int kc = 0; kc < 4; ++kc) {
    const int ko = kc * 32;
    bf16x8 a0 = *(const bf16x8*)(a0p + ko);
    bf16x8 a1 = *(const bf16x8*)(a1p + ko);
    #pragma unroll
    for (int nt = 0; nt < 8; ++nt) {
      bf16x8 bh = *(const bf16x8*)(bhp + nt * 16 * HD + ko);
      bf16x8 bl = *(const bf16x8*)(blp + nt * 16 * HD + ko);
      acc[0][nt] = __builtin_amdgcn_mfma_f32_16x16x32_bf16(a0, bh, acc[0][nt], 0, 0, 0);
      acc[0][nt] = __builtin_amdgcn_mfma_f32_16x16x32_bf16(a0, bl, acc[0][nt], 0, 0, 0);
      acc[1][nt] = __builtin_amdgcn_mfma_f32_16x16x32_bf16(a1, bh, acc[1][nt], 0, 0, 0);
      acc[1][nt] = __builtin_amdgcn_mfma_f32_16x16x32_bf16(a1, bl, acc[1][nt], 0, 0, 0);
    }
  }

  #pragma unroll
  for (int mt = 0; mt < 2; ++mt) {
    #pragma unroll
    for (int r = 0; r < 4; ++r) {
      int row = rowbase + mt * 16 + q * 4 + r;
      if (row < N) {
        float s = SCALE ? scale[row] : 1.0f;
        #pragma unroll
        for (int nt = 0; nt < 8; ++nt) {
          int col = nt * 16 + n16;
          float v = acc[mt][nt][r] + bias[col];
          if (RELU) v = fmaxf(v, 0.f);
          if (SCALE) v *= s;
          C[(size_t)row * HD + col] = f2b(v);
        }
      }
    }
  }
}

// ---------------- CSR aggregate (bf16): out[r] = relu(dis[r] * sum T[col_e]) --------
// one wave per node; lane reads one packed dword (2 bf16) per edge row (256B/row)
__global__ __launch_bounds__(256) void k_aggregate(
    const unsigned short* __restrict__ T, const int* __restrict__ offs,
    const int* __restrict__ csr_col, const float* __restrict__ dis,
    unsigned short* __restrict__ out, int N) {
  int gw = (blockIdx.x * blockDim.x + threadIdx.x) >> 6;
  int lane = threadIdx.x & 63;
  if (gw >= N) return;
  int beg = offs[gw];
  int end = offs[gw + 1];
  const unsigned int* Tl = (const unsigned int*)T + lane;
  float ax = 0.f, ay = 0.f;
  int e = beg;
  for (; e + 4 <= end; e += 4) {
    int c0 = csr_col[e + 0], c1 = csr_col[e + 1];
    int c2 = csr_col[e + 2], c3 = csr_col[e + 3];
    unsigned int v0 = Tl[(size_t)c0 * 64];
    unsigned int v1 = Tl[(size_t)c1 * 64];
    unsigned int v2 = Tl[(size_t)c2 * 64];
    unsigned int v3 = Tl[(size_t)c3 * 64];
    ax += unpack_lo(v0) + unpack_lo(v1) + unpack_lo(v2) + unpack_lo(v3);
    ay += unpack_hi(v0) + unpack_hi(v1) + unpack_hi(v2) + unpack_hi(v3);
  }
  for (; e < end; ++e) {
    unsigned int v = Tl[(size_t)csr_col[e] * 64];
    ax += unpack_lo(v);
    ay += unpack_hi(v);
  }
  float dr = dis[gw];
  float ox = fmaxf(ax * dr, 0.f);
  float oy = fmaxf(ay * dr, 0.f);
  unsigned int o = (unsigned int)f2b(ox) | ((unsigned int)f2b(oy) << 16);
  ((unsigned int*)out)[(size_t)gw * 64 + lane] = o;
}

// ---------------- mean-pool partial sums (bf16 input) ----------------
__global__ void k_pool(const unsigned short* __restrict__ X, float* __restrict__ pool, int N) {
  int c = threadIdx.x & 127;
  int half = threadIdx.x >> 7;
  int r0 = blockIdx.x * 256 + half;
  float acc = 0.f;
  for (int i = 0; i < 128; ++i) {
    int r = r0 + 2 * i;
    if (r < N) acc += b2f(X[(size_t)r * HD + c]);
  }
  atomicAdd(&pool[c], acc);
}

// ---------------- final similarity MLP (tiny, fp32) ----------------
__global__ void k_final(const float* __restrict__ pool1, const float* __restrict__ pool2,
                        const float* __restrict__ W1, const float* __restrict__ b1,
                        const float* __restrict__ W2, const float* __restrict__ b2,
                        float* __restrict__ out, float invN) {
  __shared__ float cs[512];
  __shared__ float red[2];
  int t = threadIdx.x;  // 128 threads
  float g1 = pool1[t] * invN;
  float g2 = pool2[t] * invN;
  cs[t] = g1;
  cs[128 + t] = g2;
  cs[256 + t] = fabsf(g1 - g2);
  cs[384 + t] = g1 * g2;
  __syncthreads();
  float acc = b1[t];
  #pragma unroll 8
  for (int i = 0; i < 512; ++i) acc = fmaf(cs[i], W1[(size_t)i * HD + t], acc);
  float h = fmaxf(acc, 0.f);
  float v = h * W2[t];
  #pragma unroll
  for (int off = 32; off > 0; off >>= 1) v += __shfl_down(v, off, 64);
  if ((t & 63) == 0) red[t >> 6] = v;
  __syncthreads();
  if (t == 0) out[0] = red[0] + red[1] + b2[0];
}

extern "C" void kernel_launch(void* const* d_in, const int* in_sizes, int n_in,
                              void* d_out, int out_size, void* d_ws, size_t ws_size,
                              hipStream_t stream) {
  const float* x[2]      = {(const float*)d_in[0], (const float*)d_in[2]};
  const int*   ei[2]     = {(const int*)d_in[1], (const int*)d_in[3]};
  const float* W_in[4]   = {(const float*)d_in[4], (const float*)d_in[6],
                            (const float*)d_in[8], (const float*)d_in[10]};  // enc1,enc2,conv1,conv2
  const float* B_in[4]   = {(const float*)d_in[5], (const float*)d_in[7],
                            (const float*)d_in[9], (const float*)d_in[11]};
  const float* sim_w1    = (const float*)d_in[12];
  const float* sim_b1    = (const float*)d_in[13];
  const float* sim_w2    = (const float*)d_in[14];
  const float* sim_b2    = (const float*)d_in[15];

  const int N = in_sizes[0] / HD;
  const int E = in_sizes[1] / 2;

  // workspace layout
  unsigned short* sp = (unsigned short*)d_ws;
  unsigned short* xb   = sp; sp += (size_t)N * HD;
  unsigned short* bufA = sp; sp += (size_t)N * HD;
  unsigned short* bufB = sp; sp += (size_t)N * HD;
  unsigned short* bufT = sp; sp += (size_t)N * HD;
  unsigned short* whi[4], *wlo[4];
  for (int i = 0; i < 4; ++i) { whi[i] = sp; sp += HD * HD; wlo[i] = sp; sp += HD * HD; }
  float* fp = (float*)sp;
  float* dis  = fp; fp += N;
  float* pool = fp; fp += 256;
  int* ip = (int*)fp;
  int* deg      = ip; ip += N;
  int* offs     = ip; ip += N + 1;
  int* cursor   = ip; ip += N;
  int* partials = ip; ip += 256;
  int* csr_col  = ip; ip += E;

  const int scanBlocks = (N + 255) / 256;
  const int gemmBlocks = (N + 127) / 128;
  const int aggBlocks  = (N + 3) / 4;
  const int edgeBlocks = (E + 255) / 256;
  const int cvtBlocks  = ((N * HD / 4) + 255) / 256;

  hipMemsetAsync(pool, 0, 256 * sizeof(float), stream);

  // weight convert + transpose + hi/lo split (once per call)
  for (int i = 0; i < 4; ++i)
    k_cvt_w<<<64, 256, 0, stream>>>(W_in[i], whi[i], wlo[i]);

  for (int g = 0; g < 2; ++g) {
    const int* row = ei[g];
    const int* col = ei[g] + E;

    // CSR + degree (shared by both conv layers)
    hipMemsetAsync(deg, 0, (size_t)N * sizeof(int), stream);
    k_deg_count<<<edgeBlocks, 256, 0, stream>>>(row, E, deg);
    k_scan_block<<<scanBlocks, 256, 0, stream>>>(deg, offs, partials, N);
    k_scan_partials<<<1, 256, 0, stream>>>(partials, scanBlocks);
    k_scan_finalize<<<scanBlocks, 256, 0, stream>>>(offs, partials, deg, dis, N, E);
    hipMemcpyAsync(cursor, offs, (size_t)N * sizeof(int), hipMemcpyDeviceToDevice, stream);
    k_csr_fill<<<edgeBlocks, 256, 0, stream>>>(row, col, E, cursor, csr_col);

    // x -> bf16
    k_cvt_x<<<cvtBlocks, 256, 0, stream>>>(x[g], xb, N * HD / 4);

    // encoder MLP
    k_gemm_mfma<true,  false><<<gemmBlocks, 256, 0, stream>>>(xb,   whi[0], wlo[0], B_in[0], nullptr, bufA, N);
    k_gemm_mfma<false, false><<<gemmBlocks, 256, 0, stream>>>(bufA, whi[1], wlo[1], B_in[1], nullptr, bufB, N);
    // conv1: T = (h@W+b)*dis[row]; out = relu(dis[r]*sum T[col])
    k_gemm_mfma<false, true ><<<gemmBlocks, 256, 0, stream>>>(bufB, whi[2], wlo[2], B_in[2], dis, bufT, N);
    k_aggregate<<<aggBlocks, 256, 0, stream>>>(bufT, offs, csr_col, dis, bufA, N);
    // conv2
    k_gemm_mfma<false, true ><<<gemmBlocks, 256, 0, stream>>>(bufA, whi[3], wlo[3], B_in[3], dis, bufT, N);
    k_aggregate<<<aggBlocks, 256, 0, stream>>>(bufT, offs, csr_col, dis, bufB, N);
    // mean pool (sums; divided by N in final kernel)
    k_pool<<<(N + 255) / 256, 256, 0, stream>>>(bufB, pool + g * 128, N);
  }

  k_final<<<1, 128, 0, stream>>>(pool, pool + 128, sim_w1, sim_b1, sim_w2, sim_b2,
                                 (float*)d_out, 1.0f / (float)N);
}

// Round 3
// 674.014 us; speedup vs baseline: 1.2684x; 1.1197x over previous
//
#include <hip/hip_runtime.h>
#include <hip/hip_bf16.h>

#define HD 128  // hidden/feature dim (fixed by problem)

typedef short bf16x8 __attribute__((ext_vector_type(8)));
typedef float f32x4 __attribute__((ext_vector_type(4)));

static __device__ inline unsigned short f2b(float f) {
  __hip_bfloat16 h = __float2bfloat16(f);   // RNE
  return *(unsigned short*)&h;
}
static __device__ inline float b2f(unsigned short u) {
  return __uint_as_float(((unsigned int)u) << 16);
}
static __device__ inline float unpack_lo(unsigned int v) {
  return __uint_as_float(v << 16);
}
static __device__ inline float unpack_hi(unsigned int v) {
  return __uint_as_float(v & 0xffff0000u);
}

// ---------------- degree count (both graphs, int4 edge loads) ----------------
// grid: (ceil(E/4/256), 2); non-returning atomics don't stall the wave
__global__ void k_deg_count(const int* __restrict__ ei0, const int* __restrict__ ei1,
                            int E, int N, int* __restrict__ deg2) {
  int g = blockIdx.y;
  const int* rows = (g ? ei1 : ei0);
  int base = (blockIdx.x * 256 + threadIdx.x) * 4;
  int* deg = deg2 + g * N;
  if (base + 3 < E) {
    int4 r = *(const int4*)(rows + base);
    atomicAdd(&deg[r.x], 1);
    atomicAdd(&deg[r.y], 1);
    atomicAdd(&deg[r.z], 1);
    atomicAdd(&deg[r.w], 1);
  } else {
    for (int e = base; e < E; ++e) atomicAdd(&deg[rows[e]], 1);
  }
}

// ---------------- scans over stacked deg[2N] ----------------
__global__ void k_scan_block(const int* __restrict__ deg, int* __restrict__ offs,
                             int* __restrict__ partials, int Ntot) {
  __shared__ int s[256];
  int t = threadIdx.x;
  int i = blockIdx.x * 256 + t;
  int v = (i < Ntot) ? deg[i] : 0;
  s[t] = v;
  __syncthreads();
  #pragma unroll
  for (int off = 1; off < 256; off <<= 1) {
    int x = (t >= off) ? s[t - off] : 0;
    __syncthreads();
    s[t] += x;
    __syncthreads();
  }
  if (i < Ntot) offs[i] = s[t] - v;
  if (t == 255) partials[blockIdx.x] = s[255];
}

__global__ void k_scan_partials(int* __restrict__ partials, int P) {  // 512 threads
  __shared__ int s[512];
  int t = threadIdx.x;
  int v = (t < P) ? partials[t] : 0;
  s[t] = v;
  __syncthreads();
  #pragma unroll
  for (int off = 1; off < 512; off <<= 1) {
    int x = (t >= off) ? s[t - off] : 0;
    __syncthreads();
    s[t] += x;
    __syncthreads();
  }
  if (t < P) partials[t] = s[t] - v;
}

__global__ void k_scan_finalize(int* __restrict__ offs, const int* __restrict__ partials,
                                const int* __restrict__ deg, float* __restrict__ dis,
                                int Ntot, int Etot) {
  int i = blockIdx.x * 256 + threadIdx.x;
  if (i < Ntot) {
    offs[i] += partials[blockIdx.x];
    int d = deg[i];
    dis[i] = (d > 0) ? (1.0f / sqrtf((float)d)) : 0.0f;
  }
  if (blockIdx.x == 0 && threadIdx.x == 0) offs[Ntot] = Etot;
}

// ---------------- CSR fill: ushort cols, 4 returning atomics in flight -------------
// grid: (ceil(E/4/256), 2)
__global__ void k_csr_fill(const int* __restrict__ ei0, const int* __restrict__ ei1,
                           int E, int N, int* __restrict__ cursor,
                           unsigned short* __restrict__ csr_col) {
  int g = blockIdx.y;
  const int* eg = (g ? ei1 : ei0);
  int base = (blockIdx.x * 256 + threadIdx.x) * 4;
  int* cur = cursor + g * N;
  if (base + 3 < E) {
    int4 r = *(const int4*)(eg + base);
    int4 c = *(const int4*)(eg + E + base);
    int p0 = atomicAdd(&cur[r.x], 1);
    int p1 = atomicAdd(&cur[r.y], 1);
    int p2 = atomicAdd(&cur[r.z], 1);
    int p3 = atomicAdd(&cur[r.w], 1);
    csr_col[p0] = (unsigned short)c.x;
    csr_col[p1] = (unsigned short)c.y;
    csr_col[p2] = (unsigned short)c.z;
    csr_col[p3] = (unsigned short)c.w;
  } else {
    for (int e = base; e < E; ++e) {
      int p = atomicAdd(&cur[eg[e]], 1);
      csr_col[p] = (unsigned short)eg[E + e];
    }
  }
}

// ---------------- conversions ----------------
// both x inputs -> stacked bf16 [2N,128]
__global__ void k_cvt_x(const float* __restrict__ x0, const float* __restrict__ x1,
                        unsigned short* __restrict__ O, int perGraph4) {
  int i = blockIdx.x * 256 + threadIdx.x;
  if (i < 2 * perGraph4) {
    const float* src = (i < perGraph4) ? (x0 + (size_t)i * 4)
                                       : (x1 + (size_t)(i - perGraph4) * 4);
    float4 v = *(const float4*)src;
    unsigned int p0 = (unsigned int)f2b(v.x) | ((unsigned int)f2b(v.y) << 16);
    unsigned int p1 = (unsigned int)f2b(v.z) | ((unsigned int)f2b(v.w) << 16);
    ((unsigned int*)O)[i * 2 + 0] = p0;
    ((unsigned int*)O)[i * 2 + 1] = p1;
  }
}

// all 4 weight matrices -> transposed bf16 hi/lo (stacked m*16384)
__global__ void k_cvt_w(const float* __restrict__ w0, const float* __restrict__ w1,
                        const float* __restrict__ w2, const float* __restrict__ w3,
                        unsigned short* __restrict__ hi, unsigned short* __restrict__ lo) {
  int m = blockIdx.x >> 6;
  const float* W = (m == 0) ? w0 : (m == 1) ? w1 : (m == 2) ? w2 : w3;
  int idx = (blockIdx.x & 63) * 256 + threadIdx.x;  // 0..16383
  int n = idx & 127, k = idx >> 7;
  float w = W[(size_t)k * HD + n];
  unsigned short h = f2b(w);
  size_t o = (size_t)m * 16384 + (size_t)n * HD + k;
  hi[o] = h;
  lo[o] = f2b(w - b2f(h));
}

// ---------------- MFMA GEMM over stacked [Ntot,128] ----------------
// A bf16, W pre-transposed+split bf16 hi/lo, C bf16. Wave = 32 rows x 128 cols.
template<bool RELU, bool SCALE>
__global__ __launch_bounds__(256, 2) void k_gemm_mfma(
    const unsigned short* __restrict__ A, const unsigned short* __restrict__ Whi,
    const unsigned short* __restrict__ Wlo, const float* __restrict__ bias,
    const float* __restrict__ scale, unsigned short* __restrict__ C, int Ntot) {
  const int wave = threadIdx.x >> 6;
  const int lane = threadIdx.x & 63;
  const int n16 = lane & 15;
  const int q = lane >> 4;
  const int rowbase = blockIdx.x * 128 + wave * 32;

  f32x4 acc[2][8];
  #pragma unroll
  for (int m = 0; m < 2; ++m)
    #pragma unroll
    for (int n = 0; n < 8; ++n) acc[m][n] = (f32x4){0.f, 0.f, 0.f, 0.f};

  int r0 = rowbase + n16;       if (r0 >= Ntot) r0 = Ntot - 1;
  int r1 = rowbase + 16 + n16;  if (r1 >= Ntot) r1 = Ntot - 1;
  const unsigned short* a0p = A + (size_t)r0 * HD + q * 8;
  const unsigned short* a1p = A + (size_t)r1 * HD + q * 8;
  const unsigned short* bhp = Whi + (size_t)n16 * HD + q * 8;
  const unsigned short* blp = Wlo + (size_t)n16 * HD + q * 8;

  #pragma unroll
  for (int kc = 0; kc < 4; ++kc) {
    const int ko = kc * 32;
    bf16x8 a0 = *(const bf16x8*)(a0p + ko);
    bf16x8 a1 = *(const bf16x8*)(a1p + ko);
    #pragma unroll
    for (int nt = 0; nt < 8; ++nt) {
      bf16x8 bh = *(const bf16x8*)(bhp + nt * 16 * HD + ko);
      bf16x8 bl = *(const bf16x8*)(blp + nt * 16 * HD + ko);
      acc[0][nt] = __builtin_amdgcn_mfma_f32_16x16x32_bf16(a0, bh, acc[0][nt], 0, 0, 0);
      acc[0][nt] = __builtin_amdgcn_mfma_f32_16x16x32_bf16(a0, bl, acc[0][nt], 0, 0, 0);
      acc[1][nt] = __builtin_amdgcn_mfma_f32_16x16x32_bf16(a1, bh, acc[1][nt], 0, 0, 0);
      acc[1][nt] = __builtin_amdgcn_mfma_f32_16x16x32_bf16(a1, bl, acc[1][nt], 0, 0, 0);
    }
  }

  #pragma unroll
  for (int mt = 0; mt < 2; ++mt) {
    #pragma unroll
    for (int r = 0; r < 4; ++r) {
      int row = rowbase + mt * 16 + q * 4 + r;
      if (row < Ntot) {
        float s = SCALE ? scale[row] : 1.0f;
        #pragma unroll
        for (int nt = 0; nt < 8; ++nt) {
          int col = nt * 16 + n16;
          float v = acc[mt][nt][r] + bias[col];
          if (RELU) v = fmaxf(v, 0.f);
          if (SCALE) v *= s;
          C[(size_t)row * HD + col] = f2b(v);
        }
      }
    }
  }
}

// ---------------- CSR aggregate (stacked): out[r] = relu(dis[r]*sum T[col]) --------
// one wave per node; POOL=true: skip row write, block-reduce + replica-atomic pool.
// NOTE: per-block pool graph id assumes N % 4 == 0 (block never spans graphs).
template<bool POOL>
__global__ __launch_bounds__(256) void k_aggregate(
    const unsigned short* __restrict__ T, const int* __restrict__ offs,
    const unsigned short* __restrict__ csr_col, const float* __restrict__ dis,
    unsigned short* __restrict__ out, float* __restrict__ poolrep, int N, int Ntot) {
  __shared__ float red[4][128];
  int gw = (blockIdx.x * 256 + threadIdx.x) >> 6;
  int lane = threadIdx.x & 63;
  int wave = threadIdx.x >> 6;
  float ox = 0.f, oy = 0.f;
  if (gw < Ntot) {
    int beg = offs[gw];
    int end = offs[gw + 1];
    int g = (gw >= N);
    const unsigned int* Tl = (const unsigned int*)(T + (size_t)(g ? N : 0) * HD) + lane;
    float ax = 0.f, ay = 0.f;
    int e = beg;
    for (; e + 4 <= end; e += 4) {
      int c0 = csr_col[e + 0], c1 = csr_col[e + 1];
      int c2 = csr_col[e + 2], c3 = csr_col[e + 3];
      unsigned int v0 = Tl[(size_t)c0 * 64];
      unsigned int v1 = Tl[(size_t)c1 * 64];
      unsigned int v2 = Tl[(size_t)c2 * 64];
      unsigned int v3 = Tl[(size_t)c3 * 64];
      ax += unpack_lo(v0) + unpack_lo(v1) + unpack_lo(v2) + unpack_lo(v3);
      ay += unpack_hi(v0) + unpack_hi(v1) + unpack_hi(v2) + unpack_hi(v3);
    }
    for (; e < end; ++e) {
      unsigned int v = Tl[(size_t)csr_col[e] * 64];
      ax += unpack_lo(v);
      ay += unpack_hi(v);
    }
    float dr = dis[gw];
    ox = fmaxf(ax * dr, 0.f);
    oy = fmaxf(ay * dr, 0.f);
    if (!POOL) {
      unsigned int o = (unsigned int)f2b(ox) | ((unsigned int)f2b(oy) << 16);
      ((unsigned int*)out)[(size_t)gw * 64 + lane] = o;
    }
  }
  if (POOL) {
    red[wave][2 * lane] = ox;
    red[wave][2 * lane + 1] = oy;
    __syncthreads();
    if (wave == 0) {
      float sx = red[0][2 * lane] + red[1][2 * lane] + red[2][2 * lane] + red[3][2 * lane];
      float sy = red[0][2 * lane + 1] + red[1][2 * lane + 1] + red[2][2 * lane + 1] + red[3][2 * lane + 1];
      int g = (blockIdx.x * 4 >= N);
      float* pr = poolrep + (size_t)(blockIdx.x & 15) * 256 + g * 128;
      atomicAdd(&pr[2 * lane], sx);
      atomicAdd(&pr[2 * lane + 1], sy);
    }
  }
}

// ---------------- final similarity MLP (tiny, fp32) ----------------
__global__ void k_final(const float* __restrict__ poolrep,
                        const float* __restrict__ W1, const float* __restrict__ b1,
                        const float* __restrict__ W2, const float* __restrict__ b2,
                        float* __restrict__ out, float invN) {
  __shared__ float cs[512];
  __shared__ float red[2];
  int t = threadIdx.x;  // 128 threads
  float g1 = 0.f, g2 = 0.f;
  #pragma unroll
  for (int r = 0; r < 16; ++r) {
    g1 += poolrep[r * 256 + t];
    g2 += poolrep[r * 256 + 128 + t];
  }
  g1 *= invN;
  g2 *= invN;
  cs[t] = g1;
  cs[128 + t] = g2;
  cs[256 + t] = fabsf(g1 - g2);
  cs[384 + t] = g1 * g2;
  __syncthreads();
  float acc = b1[t];
  #pragma unroll 8
  for (int i = 0; i < 512; ++i) acc = fmaf(cs[i], W1[(size_t)i * HD + t], acc);
  float h = fmaxf(acc, 0.f);
  float v = h * W2[t];
  #pragma unroll
  for (int off = 32; off > 0; off >>= 1) v += __shfl_down(v, off, 64);
  if ((t & 63) == 0) red[t >> 6] = v;
  __syncthreads();
  if (t == 0) out[0] = red[0] + red[1] + b2[0];
}

extern "C" void kernel_launch(void* const* d_in, const int* in_sizes, int n_in,
                              void* d_out, int out_size, void* d_ws, size_t ws_size,
                              hipStream_t stream) {
  const float* x1     = (const float*)d_in[0];
  const int*   ei1    = (const int*)d_in[1];
  const float* x2     = (const float*)d_in[2];
  const int*   ei2    = (const int*)d_in[3];
  const float* W_in[4] = {(const float*)d_in[4], (const float*)d_in[6],
                          (const float*)d_in[8], (const float*)d_in[10]};
  const float* B_in[4] = {(const float*)d_in[5], (const float*)d_in[7],
                          (const float*)d_in[9], (const float*)d_in[11]};
  const float* sim_w1 = (const float*)d_in[12];
  const float* sim_b1 = (const float*)d_in[13];
  const float* sim_w2 = (const float*)d_in[14];
  const float* sim_b2 = (const float*)d_in[15];

  const int N = in_sizes[0] / HD;
  const int E = in_sizes[1] / 2;
  const int Ntot = 2 * N;

  // workspace layout
  unsigned short* sp = (unsigned short*)d_ws;
  unsigned short* xb   = sp; sp += (size_t)Ntot * HD;
  unsigned short* bufA = sp; sp += (size_t)Ntot * HD;
  unsigned short* bufT = sp; sp += (size_t)Ntot * HD;
  unsigned short* whiB = sp; sp += 4 * HD * HD;
  unsigned short* wloB = sp; sp += 4 * HD * HD;
  float* fp = (float*)sp;
  float* dis     = fp; fp += Ntot;
  float* poolrep = fp; fp += 16 * 256;
  int* ip = (int*)fp;
  int* deg2     = ip; ip += Ntot;
  int* offs     = ip; ip += Ntot + 1;
  int* cursor   = ip; ip += Ntot + 1;
  int* partials = ip; ip += 512;
  unsigned short* csr_col = (unsigned short*)ip;  // 2E entries

  const int scanBlocks = (Ntot + 255) / 256;      // 391
  const int gemmBlocks = (Ntot + 127) / 128;      // 782
  const int aggBlocks  = (Ntot + 3) / 4;          // 25000
  const dim3 edgeGrid((E / 4 + 255) / 256, 2);    // int4 path; E % 4 == 0
  const int cvtBlocks  = (Ntot * (HD / 4) + 255) / 256;

  hipMemsetAsync(poolrep, 0, 16 * 256 * sizeof(float), stream);
  hipMemsetAsync(deg2, 0, (size_t)Ntot * sizeof(int), stream);

  k_cvt_w<<<256, 256, 0, stream>>>(W_in[0], W_in[1], W_in[2], W_in[3], whiB, wloB);
  k_cvt_x<<<cvtBlocks, 256, 0, stream>>>(x1, x2, xb, N * (HD / 4));

  // CSR for both graphs (stacked node space)
  k_deg_count<<<edgeGrid, 256, 0, stream>>>(ei1, ei2, E, N, deg2);
  k_scan_block<<<scanBlocks, 256, 0, stream>>>(deg2, offs, partials, Ntot);
  k_scan_partials<<<1, 512, 0, stream>>>(partials, scanBlocks);
  k_scan_finalize<<<scanBlocks, 256, 0, stream>>>(offs, partials, deg2, dis, Ntot, 2 * E);
  hipMemcpyAsync(cursor, offs, (size_t)Ntot * sizeof(int), hipMemcpyDeviceToDevice, stream);
  k_csr_fill<<<edgeGrid, 256, 0, stream>>>(ei1, ei2, E, N, cursor, csr_col);

  unsigned short* whi[4], *wlo[4];
  for (int i = 0; i < 4; ++i) { whi[i] = whiB + i * 16384; wlo[i] = wloB + i * 16384; }

  // encoder MLP (both graphs at once; shared weights)
  k_gemm_mfma<true,  false><<<gemmBlocks, 256, 0, stream>>>(xb,   whi[0], wlo[0], B_in[0], nullptr, bufA, Ntot);
  k_gemm_mfma<false, false><<<gemmBlocks, 256, 0, stream>>>(bufA, whi[1], wlo[1], B_in[1], nullptr, bufT, Ntot);
  // conv1
  k_gemm_mfma<false, true ><<<gemmBlocks, 256, 0, stream>>>(bufT, whi[2], wlo[2], B_in[2], dis, xb, Ntot);
  k_aggregate<false><<<aggBlocks, 256, 0, stream>>>(xb, offs, csr_col, dis, bufA, nullptr, N, Ntot);
  // conv2 (+ fused mean pool)
  k_gemm_mfma<false, true ><<<gemmBlocks, 256, 0, stream>>>(bufA, whi[3], wlo[3], B_in[3], dis, bufT, Ntot);
  k_aggregate<true ><<<aggBlocks, 256, 0, stream>>>(bufT, offs, csr_col, dis, nullptr, poolrep, N, Ntot);

  k_final<<<1, 128, 0, stream>>>(poolrep, sim_w1, sim_b1, sim_w2, sim_b2,
                                 (float*)d_out, 1.0f / (float)N);
}

// Round 4
// 452.331 us; speedup vs baseline: 1.8900x; 1.4901x over previous
//
#include <hip/hip_runtime.h>
#include <hip/hip_bf16.h>

#define HD 128  // hidden/feature dim (fixed by problem)

typedef short bf16x8 __attribute__((ext_vector_type(8)));
typedef float f32x4 __attribute__((ext_vector_type(4)));

static __device__ inline unsigned short f2b(float f) {
  __hip_bfloat16 h = __float2bfloat16(f);   // RNE
  return *(unsigned short*)&h;
}
static __device__ inline float b2f(unsigned short u) {
  return __uint_as_float(((unsigned int)u) << 16);
}
static __device__ inline float unpack_lo(unsigned int v) {
  return __uint_as_float(v << 16);
}
static __device__ inline float unpack_hi(unsigned int v) {
  return __uint_as_float(v & 0xffff0000u);
}
static __device__ inline unsigned int pack2(float lo, float hi) {
  return (unsigned int)f2b(lo) | ((unsigned int)f2b(hi) << 16);
}

// ---------------- degree count + per-edge slot (both graphs) ----------------
// slot[e] = old degree -> csr fill needs no atomics. 8 edges/thread.
__global__ void k_deg_slot(const int* __restrict__ ei0, const int* __restrict__ ei1,
                           int E, int N, int* __restrict__ deg2, int* __restrict__ slot) {
  int g = blockIdx.y;
  const int* rows = (g ? ei1 : ei0);
  int base = (blockIdx.x * 256 + threadIdx.x) * 8;
  int* deg = deg2 + g * N;
  int* sl = slot + g * E;
  if (base + 7 < E) {
    int4 r0 = *(const int4*)(rows + base);
    int4 r1 = *(const int4*)(rows + base + 4);
    int4 s0, s1;
    s0.x = atomicAdd(&deg[r0.x], 1);
    s0.y = atomicAdd(&deg[r0.y], 1);
    s0.z = atomicAdd(&deg[r0.z], 1);
    s0.w = atomicAdd(&deg[r0.w], 1);
    s1.x = atomicAdd(&deg[r1.x], 1);
    s1.y = atomicAdd(&deg[r1.y], 1);
    s1.z = atomicAdd(&deg[r1.z], 1);
    s1.w = atomicAdd(&deg[r1.w], 1);
    *(int4*)(sl + base) = s0;
    *(int4*)(sl + base + 4) = s1;
  } else {
    for (int e = base; e < E; ++e) sl[e] = atomicAdd(&deg[rows[e]], 1);
  }
}

// ---------------- scans over stacked deg[2N] ----------------
__global__ void k_scan_block(const int* __restrict__ deg, int* __restrict__ offs,
                             int* __restrict__ partials, int Ntot) {
  __shared__ int s[256];
  int t = threadIdx.x;
  int i = blockIdx.x * 256 + t;
  int v = (i < Ntot) ? deg[i] : 0;
  s[t] = v;
  __syncthreads();
  #pragma unroll
  for (int off = 1; off < 256; off <<= 1) {
    int x = (t >= off) ? s[t - off] : 0;
    __syncthreads();
    s[t] += x;
    __syncthreads();
  }
  if (i < Ntot) offs[i] = s[t] - v;
  if (t == 255) partials[blockIdx.x] = s[255];
}

__global__ void k_scan_partials(int* __restrict__ partials, int P) {  // 512 threads
  __shared__ int s[512];
  int t = threadIdx.x;
  int v = (t < P) ? partials[t] : 0;
  s[t] = v;
  __syncthreads();
  #pragma unroll
  for (int off = 1; off < 512; off <<= 1) {
    int x = (t >= off) ? s[t - off] : 0;
    __syncthreads();
    s[t] += x;
    __syncthreads();
  }
  if (t < P) partials[t] = s[t] - v;
}

__global__ void k_scan_finalize(int* __restrict__ offs, const int* __restrict__ partials,
                                const int* __restrict__ deg, float* __restrict__ dis,
                                int Ntot, int Etot) {
  int i = blockIdx.x * 256 + threadIdx.x;
  if (i < Ntot) {
    offs[i] += partials[blockIdx.x];
    int d = deg[i];
    dis[i] = (d > 0) ? (1.0f / sqrtf((float)d)) : 0.0f;
  }
  if (blockIdx.x == 0 && threadIdx.x == 0) offs[Ntot] = Etot;
}

// ---------------- CSR fill: no atomics (uses slot) ----------------
__global__ void k_csr_fill(const int* __restrict__ ei0, const int* __restrict__ ei1,
                           int E, int N, const int* __restrict__ offs,
                           const int* __restrict__ slot, unsigned short* __restrict__ csr_col) {
  int g = blockIdx.y;
  const int* eg = (g ? ei1 : ei0);
  const int* ob = offs + g * N;
  const int* sl = slot + g * E;
  int base = (blockIdx.x * 256 + threadIdx.x) * 4;
  if (base + 3 < E) {
    int4 r = *(const int4*)(eg + base);
    int4 c = *(const int4*)(eg + E + base);
    int4 s = *(const int4*)(sl + base);
    csr_col[ob[r.x] + s.x] = (unsigned short)c.x;
    csr_col[ob[r.y] + s.y] = (unsigned short)c.y;
    csr_col[ob[r.z] + s.z] = (unsigned short)c.z;
    csr_col[ob[r.w] + s.w] = (unsigned short)c.w;
  } else {
    for (int e = base; e < E; ++e)
      csr_col[ob[eg[e]] + sl[e]] = (unsigned short)eg[E + e];
  }
}

// ---------------- weight convert: fp32 W -> MFMA-fragment-order bf16 hi/lo --------
// Layout per matrix (32768 shorts = 64 KB): hi at [((nt*4+kc)*64+lane)*8+j],
// lo at 16384 + same, where n = 16*nt + (lane&15), k = 32*kc + 8*(lane>>4) + j.
__global__ void k_cvt_w(const float* __restrict__ w0, const float* __restrict__ w1,
                        const float* __restrict__ w2, const float* __restrict__ w3,
                        unsigned short* __restrict__ Wf) {
  int m = blockIdx.x >> 6;
  const float* W = (m == 0) ? w0 : (m == 1) ? w1 : (m == 2) ? w2 : w3;
  int idx = (blockIdx.x & 63) * 256 + threadIdx.x;  // 0..16383
  int n = idx & 127, k = idx >> 7;
  float w = W[(size_t)k * HD + n];
  unsigned short h = f2b(w);
  unsigned short l = f2b(w - b2f(h));
  int nt = n >> 4, n16 = n & 15, kc = k >> 5, q = (k >> 3) & 3, j = k & 7;
  int lanei = 16 * q + n16;
  size_t off = ((size_t)(nt * 4 + kc) * 64 + lanei) * 8 + j;
  unsigned short* base = Wf + (size_t)m * 32768;
  base[off] = h;
  base[16384 + off] = l;
}

// ---------------- MFMA GEMM, W in LDS: C = op(A @ W + b) (*scale[row]) ------------
// block = 256 (4 waves), tile = 256 rows; wave = 64 rows x 128 cols (4 m-tiles).
// W hi/lo staged to LDS in fragment order -> conflict-free ds_read_b128.
// CVT: A is fp32 (x1/x2 pair, stacked row space), converted in-kernel.
template<bool RELU, bool SCALE, bool CVT>
__global__ __launch_bounds__(256, 2) void k_gemm_lds(
    const unsigned short* __restrict__ Ab,
    const float* __restrict__ Af0, const float* __restrict__ Af1,
    const unsigned short* __restrict__ Wf, const float* __restrict__ bias,
    const float* __restrict__ scale, unsigned short* __restrict__ C,
    int N, int Ntot) {
  __shared__ unsigned short lds[32768];  // 64 KB: hi[16384] | lo[16384]
  const int tid = threadIdx.x;
  #pragma unroll
  for (int i = 0; i < 16; ++i)
    *(float4*)&lds[(size_t)(i * 256 + tid) * 8] = *(const float4*)&Wf[(size_t)(i * 256 + tid) * 8];
  __syncthreads();

  const int lane = tid & 63;
  const int wave = tid >> 6;
  const int n16 = lane & 15, q = lane >> 4;
  const int rowbase = blockIdx.x * 256 + wave * 64;

  int arow[4];
  #pragma unroll
  for (int t = 0; t < 4; ++t) {
    int r = rowbase + 16 * t + n16;
    arow[t] = (r < Ntot) ? r : (Ntot - 1);
  }

  f32x4 acc[4][8];
  #pragma unroll
  for (int t = 0; t < 4; ++t)
    #pragma unroll
    for (int nt = 0; nt < 8; ++nt) acc[t][nt] = (f32x4){0.f, 0.f, 0.f, 0.f};

  #pragma unroll
  for (int kc = 0; kc < 4; ++kc) {
    bf16x8 a[4];
    #pragma unroll
    for (int t = 0; t < 4; ++t) {
      if (CVT) {
        int r = arow[t];
        const float* src = (r < N) ? (Af0 + (size_t)r * HD) : (Af1 + (size_t)(r - N) * HD);
        float4 u0 = *(const float4*)(src + kc * 32 + q * 8);
        float4 u1 = *(const float4*)(src + kc * 32 + q * 8 + 4);
        union { unsigned short us[8]; bf16x8 v; } tmp;
        tmp.us[0] = f2b(u0.x); tmp.us[1] = f2b(u0.y);
        tmp.us[2] = f2b(u0.z); tmp.us[3] = f2b(u0.w);
        tmp.us[4] = f2b(u1.x); tmp.us[5] = f2b(u1.y);
        tmp.us[6] = f2b(u1.z); tmp.us[7] = f2b(u1.w);
        a[t] = tmp.v;
      } else {
        a[t] = *(const bf16x8*)(Ab + (size_t)arow[t] * HD + kc * 32 + q * 8);
      }
    }
    #pragma unroll
    for (int nt = 0; nt < 8; ++nt) {
      bf16x8 bh = *(const bf16x8*)&lds[(size_t)((nt * 4 + kc) * 64 + lane) * 8];
      bf16x8 bl = *(const bf16x8*)&lds[16384 + (size_t)((nt * 4 + kc) * 64 + lane) * 8];
      #pragma unroll
      for (int t = 0; t < 4; ++t) {
        acc[t][nt] = __builtin_amdgcn_mfma_f32_16x16x32_bf16(a[t], bh, acc[t][nt], 0, 0, 0);
        acc[t][nt] = __builtin_amdgcn_mfma_f32_16x16x32_bf16(a[t], bl, acc[t][nt], 0, 0, 0);
      }
    }
  }

  float bv[8];
  #pragma unroll
  for (int nt = 0; nt < 8; ++nt) bv[nt] = bias[nt * 16 + n16];

  #pragma unroll
  for (int t = 0; t < 4; ++t) {
    #pragma unroll
    for (int r = 0; r < 4; ++r) {
      int row = rowbase + 16 * t + 4 * q + r;
      if (row < Ntot) {
        float s = SCALE ? scale[row] : 1.0f;
        #pragma unroll
        for (int nt = 0; nt < 8; ++nt) {
          float v = acc[t][nt][r] + bv[nt];
          if (RELU) v = fmaxf(v, 0.f);
          if (SCALE) v *= s;
          C[(size_t)row * HD + nt * 16 + n16] = f2b(v);
        }
      }
    }
  }
}

// ---------------- CSR aggregate: out[r] = relu(dis[r]*sum T[col]) ----------------
// one wave/node; 16 lanes/row (uint4 = 16 B/lane), 4 edges per gather instruction.
template<bool POOL>
__global__ __launch_bounds__(256) void k_aggregate(
    const unsigned short* __restrict__ T, const int* __restrict__ offs,
    const unsigned short* __restrict__ csr_col, const float* __restrict__ dis,
    unsigned short* __restrict__ out, float* __restrict__ poolrep, int N, int Ntot) {
  __shared__ float red[4][128];
  const int lane = threadIdx.x & 63;
  const int wave = threadIdx.x >> 6;
  const int gw = blockIdx.x * 4 + wave;
  const int sub = lane >> 4, c16 = lane & 15;

  float ax[8];
  #pragma unroll
  for (int j = 0; j < 8; ++j) ax[j] = 0.f;

  if (gw < Ntot) {
    const int beg = offs[gw], end = offs[gw + 1];
    const unsigned int* Tg = (const unsigned int*)T + (size_t)(gw >= N ? N : 0) * 64;
    for (int e = beg; e < end; e += 16) {
      #pragma unroll
      for (int gp = 0; gp < 4; ++gp) {
        if (e + 4 * gp < end) {              // wave-uniform
          int eg = e + 4 * gp + sub;
          bool valid = (eg < end);
          int ce = valid ? eg : (end - 1);
          int col = csr_col[ce];
          uint4 v = *(const uint4*)(Tg + (size_t)col * 64 + c16 * 4);
          if (!valid) { v.x = 0; v.y = 0; v.z = 0; v.w = 0; }
          ax[0] += unpack_lo(v.x); ax[1] += unpack_hi(v.x);
          ax[2] += unpack_lo(v.y); ax[3] += unpack_hi(v.y);
          ax[4] += unpack_lo(v.z); ax[5] += unpack_hi(v.z);
          ax[6] += unpack_lo(v.w); ax[7] += unpack_hi(v.w);
        }
      }
    }
  }

  #pragma unroll
  for (int j = 0; j < 8; ++j) {
    ax[j] += __shfl_xor(ax[j], 32, 64);
    ax[j] += __shfl_xor(ax[j], 16, 64);
  }
  float dr = (gw < Ntot) ? dis[gw] : 0.f;
  #pragma unroll
  for (int j = 0; j < 8; ++j) ax[j] = fmaxf(ax[j] * dr, 0.f);

  if (!POOL) {
    if (gw < Ntot && sub == 0) {
      uint4 o;
      o.x = pack2(ax[0], ax[1]);
      o.y = pack2(ax[2], ax[3]);
      o.z = pack2(ax[4], ax[5]);
      o.w = pack2(ax[6], ax[7]);
      ((uint4*)out)[(size_t)gw * 16 + c16] = o;
    }
  } else {
    if (sub == 0) {
      *(float4*)&red[wave][c16 * 8]     = make_float4(ax[0], ax[1], ax[2], ax[3]);
      *(float4*)&red[wave][c16 * 8 + 4] = make_float4(ax[4], ax[5], ax[6], ax[7]);
    }
    __syncthreads();
    int t = threadIdx.x;
    if (t < 128) {
      float s = red[0][t] + red[1][t] + red[2][t] + red[3][t];
      int g = (blockIdx.x * 4 >= N) ? 1 : 0;
      atomicAdd(&poolrep[(size_t)((blockIdx.x & 15) * 2 + g) * 128 + t], s);
    }
  }
}

// ---------------- final similarity MLP (tiny, fp32) ----------------
__global__ void k_final(const float* __restrict__ poolrep,
                        const float* __restrict__ W1, const float* __restrict__ b1,
                        const float* __restrict__ W2, const float* __restrict__ b2,
                        float* __restrict__ out, float invN) {
  __shared__ float cs[512];
  __shared__ float red[2];
  int t = threadIdx.x;  // 128 threads
  float g1 = 0.f, g2 = 0.f;
  #pragma unroll
  for (int r = 0; r < 16; ++r) {
    g1 += poolrep[r * 256 + t];
    g2 += poolrep[r * 256 + 128 + t];
  }
  g1 *= invN;
  g2 *= invN;
  cs[t] = g1;
  cs[128 + t] = g2;
  cs[256 + t] = fabsf(g1 - g2);
  cs[384 + t] = g1 * g2;
  __syncthreads();
  float acc = b1[t];
  #pragma unroll 8
  for (int i = 0; i < 512; ++i) acc = fmaf(cs[i], W1[(size_t)i * HD + t], acc);
  float h = fmaxf(acc, 0.f);
  float v = h * W2[t];
  #pragma unroll
  for (int off = 32; off > 0; off >>= 1) v += __shfl_down(v, off, 64);
  if ((t & 63) == 0) red[t >> 6] = v;
  __syncthreads();
  if (t == 0) out[0] = red[0] + red[1] + b2[0];
}

extern "C" void kernel_launch(void* const* d_in, const int* in_sizes, int n_in,
                              void* d_out, int out_size, void* d_ws, size_t ws_size,
                              hipStream_t stream) {
  const float* x1     = (const float*)d_in[0];
  const int*   ei1    = (const int*)d_in[1];
  const float* x2     = (const float*)d_in[2];
  const int*   ei2    = (const int*)d_in[3];
  const float* W_in[4] = {(const float*)d_in[4], (const float*)d_in[6],
                          (const float*)d_in[8], (const float*)d_in[10]};
  const float* B_in[4] = {(const float*)d_in[5], (const float*)d_in[7],
                          (const float*)d_in[9], (const float*)d_in[11]};
  const float* sim_w1 = (const float*)d_in[12];
  const float* sim_b1 = (const float*)d_in[13];
  const float* sim_w2 = (const float*)d_in[14];
  const float* sim_b2 = (const float*)d_in[15];

  const int N = in_sizes[0] / HD;
  const int E = in_sizes[1] / 2;
  const int Ntot = 2 * N;

  // workspace layout (16B-aligned chunks first)
  unsigned short* sp = (unsigned short*)d_ws;
  unsigned short* bufA = sp; sp += (size_t)Ntot * HD;
  unsigned short* bufB = sp; sp += (size_t)Ntot * HD;
  unsigned short* Wf   = sp; sp += 4 * 32768;
  float* fp = (float*)sp;
  float* dis     = fp; fp += Ntot;
  float* poolrep = fp; fp += 16 * 256;
  int* ip = (int*)fp;
  int* deg2     = ip; ip += Ntot;
  int* offs     = ip; ip += Ntot + 1;
  int* partials = ip; ip += 512;
  ip += 1;  // realign to 8B/16B boundary for int4 slot stores
  int* slot     = ip; ip += 2 * E;
  unsigned short* csr_col = (unsigned short*)ip;  // 2E entries

  const int scanBlocks = (Ntot + 255) / 256;
  const int gemmBlocks = (Ntot + 255) / 256;
  const int aggBlocks  = (Ntot + 3) / 4;
  const dim3 degGrid((E / 8 + 255) / 256, 2);
  const dim3 fillGrid((E / 4 + 255) / 256, 2);

  hipMemsetAsync(poolrep, 0, 16 * 256 * sizeof(float), stream);
  hipMemsetAsync(deg2, 0, (size_t)Ntot * sizeof(int), stream);

  k_cvt_w<<<256, 256, 0, stream>>>(W_in[0], W_in[1], W_in[2], W_in[3], Wf);

  // CSR for both graphs (stacked node space), atomic-free fill via slots
  k_deg_slot<<<degGrid, 256, 0, stream>>>(ei1, ei2, E, N, deg2, slot);
  k_scan_block<<<scanBlocks, 256, 0, stream>>>(deg2, offs, partials, Ntot);
  k_scan_partials<<<1, 512, 0, stream>>>(partials, scanBlocks);
  k_scan_finalize<<<scanBlocks, 256, 0, stream>>>(offs, partials, deg2, dis, Ntot, 2 * E);
  k_csr_fill<<<fillGrid, 256, 0, stream>>>(ei1, ei2, E, N, offs, slot, csr_col);

  // encoder MLP (both graphs; fp32->bf16 convert fused into enc1)
  k_gemm_lds<true,  false, true ><<<gemmBlocks, 256, 0, stream>>>(
      nullptr, x1, x2, Wf + 0 * 32768, B_in[0], nullptr, bufA, N, Ntot);
  k_gemm_lds<false, false, false><<<gemmBlocks, 256, 0, stream>>>(
      bufA, nullptr, nullptr, Wf + 1 * 32768, B_in[1], nullptr, bufB, N, Ntot);
  // conv1: T = (h@W+b)*dis[row]; out = relu(dis[r]*sum T[col])
  k_gemm_lds<false, true,  false><<<gemmBlocks, 256, 0, stream>>>(
      bufB, nullptr, nullptr, Wf + 2 * 32768, B_in[2], dis, bufA, N, Ntot);
  k_aggregate<false><<<aggBlocks, 256, 0, stream>>>(bufA, offs, csr_col, dis, bufB, nullptr, N, Ntot);
  // conv2 (+ fused mean pool)
  k_gemm_lds<false, true,  false><<<gemmBlocks, 256, 0, stream>>>(
      bufB, nullptr, nullptr, Wf + 3 * 32768, B_in[3], dis, bufA, N, Ntot);
  k_aggregate<true ><<<aggBlocks, 256, 0, stream>>>(bufA, offs, csr_col, dis, nullptr, poolrep, N, Ntot);

  k_final<<<1, 128, 0, stream>>>(poolrep, sim_w1, sim_b1, sim_w2, sim_b2,
                                 (float*)d_out, 1.0f / (float)N);
}

// Round 5
// 423.528 us; speedup vs baseline: 2.0186x; 1.0680x over previous
//
#include <hip/hip_runtime.h>
#include <hip/hip_bf16.h>

#define HD 128  // hidden/feature dim (fixed by problem)

typedef _Float16 f16x8 __attribute__((ext_vector_type(8)));
typedef _Float16 f16x2 __attribute__((ext_vector_type(2)));
typedef float f32x4 __attribute__((ext_vector_type(4)));

// ---------------- degree count + per-edge slot (both graphs) ----------------
// slot[e] = old degree (ushort) -> csr fill needs no atomics. 8 edges/thread.
__global__ void k_deg_slot(const int* __restrict__ ei0, const int* __restrict__ ei1,
                           int E, int N, int* __restrict__ deg2,
                           unsigned short* __restrict__ slot) {
  int g = blockIdx.y;
  const int* rows = (g ? ei1 : ei0);
  int base = (blockIdx.x * 256 + threadIdx.x) * 8;
  int* deg = deg2 + g * N;
  unsigned short* sl = slot + (size_t)g * E;
  if (base + 7 < E) {
    int4 r0 = *(const int4*)(rows + base);
    int4 r1 = *(const int4*)(rows + base + 4);
    union { unsigned short us[8]; uint4 v; } s;
    s.us[0] = (unsigned short)atomicAdd(&deg[r0.x], 1);
    s.us[1] = (unsigned short)atomicAdd(&deg[r0.y], 1);
    s.us[2] = (unsigned short)atomicAdd(&deg[r0.z], 1);
    s.us[3] = (unsigned short)atomicAdd(&deg[r0.w], 1);
    s.us[4] = (unsigned short)atomicAdd(&deg[r1.x], 1);
    s.us[5] = (unsigned short)atomicAdd(&deg[r1.y], 1);
    s.us[6] = (unsigned short)atomicAdd(&deg[r1.z], 1);
    s.us[7] = (unsigned short)atomicAdd(&deg[r1.w], 1);
    *(uint4*)(sl + base) = s.v;
  } else {
    for (int e = base; e < E; ++e)
      sl[e] = (unsigned short)atomicAdd(&deg[rows[e]], 1);
  }
}

// ---------------- scans over stacked deg[2N] ----------------
__global__ void k_scan_block(const int* __restrict__ deg, int* __restrict__ offs,
                             int* __restrict__ partials, int Ntot) {
  __shared__ int s[256];
  int t = threadIdx.x;
  int i = blockIdx.x * 256 + t;
  int v = (i < Ntot) ? deg[i] : 0;
  s[t] = v;
  __syncthreads();
  #pragma unroll
  for (int off = 1; off < 256; off <<= 1) {
    int x = (t >= off) ? s[t - off] : 0;
    __syncthreads();
    s[t] += x;
    __syncthreads();
  }
  if (i < Ntot) offs[i] = s[t] - v;
  if (t == 255) partials[blockIdx.x] = s[255];
}

__global__ void k_scan_partials(int* __restrict__ partials, int P) {  // 512 threads
  __shared__ int s[512];
  int t = threadIdx.x;
  int v = (t < P) ? partials[t] : 0;
  s[t] = v;
  __syncthreads();
  #pragma unroll
  for (int off = 1; off < 512; off <<= 1) {
    int x = (t >= off) ? s[t - off] : 0;
    __syncthreads();
    s[t] += x;
    __syncthreads();
  }
  if (t < P) partials[t] = s[t] - v;
}

__global__ void k_scan_finalize(int* __restrict__ offs, const int* __restrict__ partials,
                                const int* __restrict__ deg, float* __restrict__ dis,
                                int Ntot, int Etot) {
  int i = blockIdx.x * 256 + threadIdx.x;
  if (i < Ntot) {
    offs[i] += partials[blockIdx.x];
    int d = deg[i];
    dis[i] = (d > 0) ? (1.0f / sqrtf((float)d)) : 0.0f;
  }
  if (blockIdx.x == 0 && threadIdx.x == 0) offs[Ntot] = Etot;
}

// ---------------- CSR fill: no atomics (uses ushort slot) ----------------
__global__ void k_csr_fill(const int* __restrict__ ei0, const int* __restrict__ ei1,
                           int E, int N, const int* __restrict__ offs,
                           const unsigned short* __restrict__ slot,
                           unsigned short* __restrict__ csr_col) {
  int g = blockIdx.y;
  const int* eg = (g ? ei1 : ei0);
  const int* ob = offs + g * N;
  const unsigned short* sl = slot + (size_t)g * E;
  int base = (blockIdx.x * 256 + threadIdx.x) * 4;
  if (base + 3 < E) {
    int4 r = *(const int4*)(eg + base);
    int4 c = *(const int4*)(eg + E + base);
    uint2 sv = *(const uint2*)(sl + base);
    csr_col[ob[r.x] + (sv.x & 0xffff)] = (unsigned short)c.x;
    csr_col[ob[r.y] + (sv.x >> 16)]   = (unsigned short)c.y;
    csr_col[ob[r.z] + (sv.y & 0xffff)] = (unsigned short)c.z;
    csr_col[ob[r.w] + (sv.y >> 16)]   = (unsigned short)c.w;
  } else {
    for (int e = base; e < E; ++e)
      csr_col[ob[eg[e]] + sl[e]] = (unsigned short)eg[E + e];
  }
}

// ---------------- weight convert: fp32 W -> MFMA-fragment-order f16 --------
// Layout per matrix (16384 halves = 32 KB): at [((nt*4+kc)*64+lane)*8+j],
// where n = 16*nt + (lane&15), k = 32*kc + 8*(lane>>4) + j.
__global__ void k_cvt_w(const float* __restrict__ w0, const float* __restrict__ w1,
                        const float* __restrict__ w2, const float* __restrict__ w3,
                        _Float16* __restrict__ Wf) {
  int m = blockIdx.x >> 6;
  const float* W = (m == 0) ? w0 : (m == 1) ? w1 : (m == 2) ? w2 : w3;
  int idx = (blockIdx.x & 63) * 256 + threadIdx.x;  // 0..16383
  int n = idx & 127, k = idx >> 7;
  float w = W[(size_t)k * HD + n];
  int nt = n >> 4, n16 = n & 15, kc = k >> 5, q = (k >> 3) & 3, j = k & 7;
  int lanei = 16 * q + n16;
  size_t off = ((size_t)(nt * 4 + kc) * 64 + lanei) * 8 + j;
  Wf[(size_t)m * 16384 + off] = (_Float16)w;
}

// ---------------- MFMA GEMM, W in LDS: C = op(A @ W + b) (*scale[row]) ------------
// block = 256 (4 waves), tile = 256 rows; wave = 64 rows x 128 cols (4 m-tiles).
// f16 everywhere; hi-only weights. CVT: A is fp32 (x1/x2 pair), converted in-kernel.
template<bool RELU, bool SCALE, bool CVT>
__global__ __launch_bounds__(256, 2) void k_gemm_lds(
    const _Float16* __restrict__ Ab,
    const float* __restrict__ Af0, const float* __restrict__ Af1,
    const _Float16* __restrict__ Wf, const float* __restrict__ bias,
    const float* __restrict__ scale, _Float16* __restrict__ C,
    int N, int Ntot) {
  __shared__ _Float16 lds[16384];  // 32 KB
  const int tid = threadIdx.x;
  #pragma unroll
  for (int i = 0; i < 8; ++i)
    *(float4*)&lds[(size_t)(i * 256 + tid) * 8] = *(const float4*)&Wf[(size_t)(i * 256 + tid) * 8];
  __syncthreads();

  const int lane = tid & 63;
  const int wave = tid >> 6;
  const int n16 = lane & 15, q = lane >> 4;
  const int rowbase = blockIdx.x * 256 + wave * 64;

  int arow[4];
  #pragma unroll
  for (int t = 0; t < 4; ++t) {
    int r = rowbase + 16 * t + n16;
    arow[t] = (r < Ntot) ? r : (Ntot - 1);
  }

  f32x4 acc[4][8];
  #pragma unroll
  for (int t = 0; t < 4; ++t)
    #pragma unroll
    for (int nt = 0; nt < 8; ++nt) acc[t][nt] = (f32x4){0.f, 0.f, 0.f, 0.f};

  #pragma unroll
  for (int kc = 0; kc < 4; ++kc) {
    f16x8 a[4];
    #pragma unroll
    for (int t = 0; t < 4; ++t) {
      if (CVT) {
        int r = arow[t];
        const float* src = (r < N) ? (Af0 + (size_t)r * HD) : (Af1 + (size_t)(r - N) * HD);
        float4 u0 = *(const float4*)(src + kc * 32 + q * 8);
        float4 u1 = *(const float4*)(src + kc * 32 + q * 8 + 4);
        union { _Float16 h[8]; f16x8 v; } tmp;
        tmp.h[0] = (_Float16)u0.x; tmp.h[1] = (_Float16)u0.y;
        tmp.h[2] = (_Float16)u0.z; tmp.h[3] = (_Float16)u0.w;
        tmp.h[4] = (_Float16)u1.x; tmp.h[5] = (_Float16)u1.y;
        tmp.h[6] = (_Float16)u1.z; tmp.h[7] = (_Float16)u1.w;
        a[t] = tmp.v;
      } else {
        a[t] = *(const f16x8*)(Ab + (size_t)arow[t] * HD + kc * 32 + q * 8);
      }
    }
    #pragma unroll
    for (int nt = 0; nt < 8; ++nt) {
      f16x8 b = *(const f16x8*)&lds[(size_t)((nt * 4 + kc) * 64 + lane) * 8];
      #pragma unroll
      for (int t = 0; t < 4; ++t)
        acc[t][nt] = __builtin_amdgcn_mfma_f32_16x16x32_f16(a[t], b, acc[t][nt], 0, 0, 0);
    }
  }

  float bv[8];
  #pragma unroll
  for (int nt = 0; nt < 8; ++nt) bv[nt] = bias[nt * 16 + n16];

  #pragma unroll
  for (int t = 0; t < 4; ++t) {
    #pragma unroll
    for (int r = 0; r < 4; ++r) {
      int row = rowbase + 16 * t + 4 * q + r;
      if (row < Ntot) {
        float s = SCALE ? scale[row] : 1.0f;
        #pragma unroll
        for (int nt = 0; nt < 8; ++nt) {
          float v = acc[t][nt][r] + bv[nt];
          if (RELU) v = fmaxf(v, 0.f);
          if (SCALE) v *= s;
          C[(size_t)row * HD + nt * 16 + n16] = (_Float16)v;
        }
      }
    }
  }
}

// ---------------- CSR aggregate: out[r] = relu(dis[r]*sum T[col]) ----------------
// one wave/node; 16 lanes/row (uint4 = 8 f16/lane), 4 edges per gather instruction.
// Messages accumulated as packed f16 pairs (v_pk_add_f16), final reduce in fp32.
template<bool POOL>
__global__ __launch_bounds__(256) void k_aggregate(
    const _Float16* __restrict__ T, const int* __restrict__ offs,
    const unsigned short* __restrict__ csr_col, const float* __restrict__ dis,
    _Float16* __restrict__ out, float* __restrict__ poolrep, int N, int Ntot) {
  __shared__ float red[4][128];
  const int lane = threadIdx.x & 63;
  const int wave = threadIdx.x >> 6;
  const int gw = blockIdx.x * 4 + wave;
  const int sub = lane >> 4, c16 = lane & 15;

  f16x2 hacc[4];
  #pragma unroll
  for (int j = 0; j < 4; ++j) hacc[j] = (f16x2){(_Float16)0.f, (_Float16)0.f};

  if (gw < Ntot) {
    const int beg = offs[gw], end = offs[gw + 1];
    const uint4* Tg = (const uint4*)(T + (size_t)(gw >= N ? N : 0) * HD);
    for (int e = beg; e < end; e += 16) {
      uint4 v[4];
      #pragma unroll
      for (int gp = 0; gp < 4; ++gp) {
        v[gp] = make_uint4(0, 0, 0, 0);
        if (e + 4 * gp < end) {              // wave-uniform
          int eg = e + 4 * gp + sub;
          bool valid = (eg < end);
          int ce = valid ? eg : (end - 1);
          int col = csr_col[ce];
          uint4 t = Tg[(size_t)col * 16 + c16];
          if (valid) v[gp] = t;
        }
      }
      #pragma unroll
      for (int gp = 0; gp < 4; ++gp) {
        union { uint4 u; f16x2 h[4]; } w;
        w.u = v[gp];
        hacc[0] += w.h[0];
        hacc[1] += w.h[1];
        hacc[2] += w.h[2];
        hacc[3] += w.h[3];
      }
    }
  }

  float ax[8];
  #pragma unroll
  for (int j = 0; j < 4; ++j) {
    ax[2 * j]     = (float)hacc[j][0];
    ax[2 * j + 1] = (float)hacc[j][1];
  }
  #pragma unroll
  for (int j = 0; j < 8; ++j) {
    ax[j] += __shfl_xor(ax[j], 32, 64);
    ax[j] += __shfl_xor(ax[j], 16, 64);
  }
  float dr = (gw < Ntot) ? dis[gw] : 0.f;
  #pragma unroll
  for (int j = 0; j < 8; ++j) ax[j] = fmaxf(ax[j] * dr, 0.f);

  if (!POOL) {
    if (gw < Ntot && sub == 0) {
      union { uint4 u; _Float16 h[8]; } o;
      #pragma unroll
      for (int j = 0; j < 8; ++j) o.h[j] = (_Float16)ax[j];
      ((uint4*)out)[(size_t)gw * 16 + c16] = o.u;
    }
  } else {
    if (sub == 0) {
      *(float4*)&red[wave][c16 * 8]     = make_float4(ax[0], ax[1], ax[2], ax[3]);
      *(float4*)&red[wave][c16 * 8 + 4] = make_float4(ax[4], ax[5], ax[6], ax[7]);
    }
    __syncthreads();
    int t = threadIdx.x;
    if (t < 128) {
      float s = red[0][t] + red[1][t] + red[2][t] + red[3][t];
      int g = (blockIdx.x * 4 >= N) ? 1 : 0;
      atomicAdd(&poolrep[(size_t)((blockIdx.x & 15) * 2 + g) * 128 + t], s);
    }
  }
}

// ---------------- final similarity MLP (tiny, fp32) ----------------
__global__ void k_final(const float* __restrict__ poolrep,
                        const float* __restrict__ W1, const float* __restrict__ b1,
                        const float* __restrict__ W2, const float* __restrict__ b2,
                        float* __restrict__ out, float invN) {
  __shared__ float cs[512];
  __shared__ float red[2];
  int t = threadIdx.x;  // 128 threads
  float g1 = 0.f, g2 = 0.f;
  #pragma unroll
  for (int r = 0; r < 16; ++r) {
    g1 += poolrep[r * 256 + t];
    g2 += poolrep[r * 256 + 128 + t];
  }
  g1 *= invN;
  g2 *= invN;
  cs[t] = g1;
  cs[128 + t] = g2;
  cs[256 + t] = fabsf(g1 - g2);
  cs[384 + t] = g1 * g2;
  __syncthreads();
  float acc = b1[t];
  #pragma unroll 8
  for (int i = 0; i < 512; ++i) acc = fmaf(cs[i], W1[(size_t)i * HD + t], acc);
  float h = fmaxf(acc, 0.f);
  float v = h * W2[t];
  #pragma unroll
  for (int off = 32; off > 0; off >>= 1) v += __shfl_down(v, off, 64);
  if ((t & 63) == 0) red[t >> 6] = v;
  __syncthreads();
  if (t == 0) out[0] = red[0] + red[1] + b2[0];
}

extern "C" void kernel_launch(void* const* d_in, const int* in_sizes, int n_in,
                              void* d_out, int out_size, void* d_ws, size_t ws_size,
                              hipStream_t stream) {
  const float* x1     = (const float*)d_in[0];
  const int*   ei1    = (const int*)d_in[1];
  const float* x2     = (const float*)d_in[2];
  const int*   ei2    = (const int*)d_in[3];
  const float* W_in[4] = {(const float*)d_in[4], (const float*)d_in[6],
                          (const float*)d_in[8], (const float*)d_in[10]};
  const float* B_in[4] = {(const float*)d_in[5], (const float*)d_in[7],
                          (const float*)d_in[9], (const float*)d_in[11]};
  const float* sim_w1 = (const float*)d_in[12];
  const float* sim_b1 = (const float*)d_in[13];
  const float* sim_w2 = (const float*)d_in[14];
  const float* sim_b2 = (const float*)d_in[15];

  const int N = in_sizes[0] / HD;
  const int E = in_sizes[1] / 2;
  const int Ntot = 2 * N;

  // workspace layout (16B-aligned chunks first)
  _Float16* sp = (_Float16*)d_ws;
  _Float16* bufA = sp; sp += (size_t)Ntot * HD;
  _Float16* bufB = sp; sp += (size_t)Ntot * HD;
  _Float16* Wf   = sp; sp += 4 * 16384;
  float* fp = (float*)sp;
  float* dis     = fp; fp += Ntot;
  float* poolrep = fp; fp += 16 * 256;   // zeroed together with deg2 (adjacent)
  int* ip = (int*)fp;
  int* deg2     = ip; ip += Ntot;
  int* offs     = ip; ip += Ntot + 1;
  int* partials = ip; ip += 512;
  // align to 16B for uint4 slot stores
  ip = (int*)(((uintptr_t)ip + 15) & ~(uintptr_t)15);
  unsigned short* slot = (unsigned short*)ip;       // 2E ushorts
  unsigned short* csr_col = slot + 2 * (size_t)E;   // 2E ushorts

  const int scanBlocks = (Ntot + 255) / 256;
  const int gemmBlocks = (Ntot + 255) / 256;
  const int aggBlocks  = (Ntot + 3) / 4;
  const dim3 degGrid((E / 8 + 255) / 256, 2);
  const dim3 fillGrid((E / 4 + 255) / 256, 2);

  // poolrep + deg2 are adjacent: one memset
  hipMemsetAsync(poolrep, 0, (16 * 256 + Ntot) * sizeof(float), stream);

  k_cvt_w<<<256, 256, 0, stream>>>(W_in[0], W_in[1], W_in[2], W_in[3], Wf);

  // CSR for both graphs (stacked node space), atomic-free fill via ushort slots
  k_deg_slot<<<degGrid, 256, 0, stream>>>(ei1, ei2, E, N, deg2, slot);
  k_scan_block<<<scanBlocks, 256, 0, stream>>>(deg2, offs, partials, Ntot);
  k_scan_partials<<<1, 512, 0, stream>>>(partials, scanBlocks);
  k_scan_finalize<<<scanBlocks, 256, 0, stream>>>(offs, partials, deg2, dis, Ntot, 2 * E);
  k_csr_fill<<<fillGrid, 256, 0, stream>>>(ei1, ei2, E, N, offs, slot, csr_col);

  // encoder MLP (both graphs; fp32->f16 convert fused into enc1)
  k_gemm_lds<true,  false, true ><<<gemmBlocks, 256, 0, stream>>>(
      nullptr, x1, x2, Wf + 0 * 16384, B_in[0], nullptr, bufA, N, Ntot);
  k_gemm_lds<false, false, false><<<gemmBlocks, 256, 0, stream>>>(
      bufA, nullptr, nullptr, Wf + 1 * 16384, B_in[1], nullptr, bufB, N, Ntot);
  // conv1: T = (h@W+b)*dis[row]; out = relu(dis[r]*sum T[col])
  k_gemm_lds<false, true,  false><<<gemmBlocks, 256, 0, stream>>>(
      bufB, nullptr, nullptr, Wf + 2 * 16384, B_in[2], dis, bufA, N, Ntot);
  k_aggregate<false><<<aggBlocks, 256, 0, stream>>>(bufA, offs, csr_col, dis, bufB, nullptr, N, Ntot);
  // conv2 (+ fused mean pool)
  k_gemm_lds<false, true,  false><<<gemmBlocks, 256, 0, stream>>>(
      bufB, nullptr, nullptr, Wf + 3 * 16384, B_in[3], dis, bufA, N, Ntot);
  k_aggregate<true ><<<aggBlocks, 256, 0, stream>>>(bufA, offs, csr_col, dis, nullptr, poolrep, N, Ntot);

  k_final<<<1, 128, 0, stream>>>(poolrep, sim_w1, sim_b1, sim_w2, sim_b2,
                                 (float*)d_out, 1.0f / (float)N);
}